// Round 11
// baseline (341.466 us; speedup 1.0000x reference)
//
#include <hip/hip_runtime.h>

#define BS   8192
#define DIM  1024
#define TINV 10.0f    // 1 / TEMPERATURE
#define MARGIN 1.0f   // max(0.01, 1.0 - 0.1*0.0)

#define BM  128
#define BN  64
#define BKB 128       // fp8 K-bytes per staging iteration (16x16x128 MFMA)

// fp8 values are the normalized elements scaled by 16 -> dot = 256 * cos
#define QSCALE   16.0f
#define INV_QSQ  (1.0f / 256.0f)

typedef __attribute__((ext_vector_type(4))) float f32x4;
typedef __attribute__((ext_vector_type(4))) int   int4v;
typedef __attribute__((ext_vector_type(8))) int   int8v;

// ---------------- Kernel 1: L2-normalize rows (one wave per row, R10) -------
__global__ __launch_bounds__(256) void normalize_kernel(
    const float* __restrict__ feat,
    unsigned char* __restrict__ Afp8,
    unsigned char* __restrict__ Nfp8,
    float* __restrict__ posdist)
{
    const int lane = threadIdx.x & 63;
    const int row  = blockIdx.x * 4 + (threadIdx.x >> 6);   // wave = row

    const float4* fo = (const float4*)(feat + (size_t)row * DIM);
    const float4* fp = (const float4*)(feat + (size_t)(BS + row) * DIM);
    const float4* fn = (const float4*)(feat + (size_t)(2 * BS + row) * DIM);

    float4 o[4], p[4], n[4];
    #pragma unroll
    for (int k = 0; k < 4; k++) {
        o[k] = fo[lane + 64 * k];
        p[k] = fp[lane + 64 * k];
        n[k] = fn[lane + 64 * k];
    }

    float so = 0.f, sp = 0.f, sn = 0.f;
    #pragma unroll
    for (int k = 0; k < 4; k++) {
        so += o[k].x*o[k].x + o[k].y*o[k].y + o[k].z*o[k].z + o[k].w*o[k].w;
        sp += p[k].x*p[k].x + p[k].y*p[k].y + p[k].z*p[k].z + p[k].w*p[k].w;
        sn += n[k].x*n[k].x + n[k].y*n[k].y + n[k].z*n[k].z + n[k].w*n[k].w;
    }
    #pragma unroll
    for (int off = 1; off < 64; off <<= 1) {
        so += __shfl_xor(so, off);
        sp += __shfl_xor(sp, off);
        sn += __shfl_xor(sn, off);
    }

    const float io  = 1.0f / fmaxf(sqrtf(so), 1e-12f);
    const float ip  = 1.0f / fmaxf(sqrtf(sp), 1e-12f);
    const float in_ = 1.0f / fmaxf(sqrtf(sn), 1e-12f);

    int* Ar = (int*)(Afp8 + (size_t)row * DIM);
    int* Nr = (int*)(Nfp8 + (size_t)row * DIM);

    float d = 0.f;
    #pragma unroll
    for (int k = 0; k < 4; k++) {
        float ax = o[k].x*io, ay = o[k].y*io, az = o[k].z*io, aw = o[k].w*io;
        float nx = n[k].x*in_, ny = n[k].y*in_, nz = n[k].z*in_, nw = n[k].w*in_;
        int pa = __builtin_amdgcn_cvt_pk_fp8_f32(ax*QSCALE, ay*QSCALE, 0, false);
        pa     = __builtin_amdgcn_cvt_pk_fp8_f32(az*QSCALE, aw*QSCALE, pa, true);
        int pn = __builtin_amdgcn_cvt_pk_fp8_f32(nx*QSCALE, ny*QSCALE, 0, false);
        pn     = __builtin_amdgcn_cvt_pk_fp8_f32(nz*QSCALE, nw*QSCALE, pn, true);
        Ar[lane + 64 * k] = pa;      // coalesced 4B stores
        Nr[lane + 64 * k] = pn;
        float dx = ax - p[k].x*ip, dy = ay - p[k].y*ip;
        float dz = az - p[k].z*ip, dw = aw - p[k].w*ip;
        d += dx*dx + dy*dy + dz*dz + dw*dw;
    }
    #pragma unroll
    for (int off = 1; off < 64; off <<= 1) d += __shfl_xor(d, off);
    if (lane == 0) posdist[row] = d * TINV;
}

// ---------------- Kernel 2: MX-fp8 16x16x128 MFMA max-GEMM ------------------
// R11: FRAGMENT-MAJOR LDS layout. R9/R10 measured exactly 4.0 conflict-cycles
// per dual-b128 fragment read (SQ_LDS_BANK_CONFLICT 1.26e7 ~= 18% of cycles).
// Now each 16-row x 128B MFMA tile is stored as lane-order fragments:
//   [tile*2048 + 0    .. 1024) = lo 16B-halves of lanes 0..63
//   [tile*2048 + 1024 .. 2048) = hi 16B-halves
// Fragment read = two ds_read_b128 at base+16*lane (+1024): the canonical
// conflict-free stride-16 pattern (same as global_load_lds's own writes).
// All 12 inner reads use ONE per-lane base + immediate offsets (no XOR math).
// Staging: tile t, phase ph: lane L=(q*16+m) fetches global row m of tile t,
// 16B chunk (2q+ph) -> LDS tile t + ph*1024 + 16L (lane h=q owns k-bytes
// [32h,32h+32): lo chunk 2h, hi chunk 2h+1 -- matches the fragment mapping
// verified by R5-R10's absmax=0).
__global__ __launch_bounds__(256) void maxgemm_kernel(
    const unsigned char* __restrict__ Afp8,
    const unsigned char* __restrict__ Nfp8,
    float* __restrict__ partial)   // [BS][128] row-major
{
    __shared__ unsigned char As[BM * BKB];   // 8 tiles x 2048 B
    __shared__ unsigned char Bs[BN * BKB];   // 4 tiles x 2048 B

    const int tid  = threadIdx.x;
    const int lane = tid & 63;
    const int w    = tid >> 6;
    const int rowBase = blockIdx.y * BM;
    const int colBase = blockIdx.x * BN;

    const int m = lane & 15;          // row within 16-row tile
    const int q = lane >> 4;          // k-quad: owns chunks 2q, 2q+1

    // Per-lane global staging bases (tile adds t*16*DIM, phase adds 16, iter k0)
    const unsigned char* AgL = Afp8 + (size_t)(rowBase + m) * DIM + q * 32;
    const unsigned char* BgL = Nfp8 + (size_t)(colBase + m) * DIM + q * 32;

    // Per-lane LDS read bases; all fragment reads are immediate offsets off these
    const unsigned char* aRd = As + (size_t)w * 4096 + lane * 16;  // tiles w*2+i
    const unsigned char* bRd = Bs + lane * 16;                     // tiles j

    f32x4 acc[2][4];
    #pragma unroll
    for (int i = 0; i < 2; i++)
        #pragma unroll
        for (int j = 0; j < 4; j++)
            acc[i][j] = (f32x4){0.f, 0.f, 0.f, 0.f};

    for (int k0 = 0; k0 < DIM; k0 += BKB) {
        __syncthreads();  // prior iter's LDS reads done
        #pragma unroll
        for (int t2 = 0; t2 < 2; t2++) {        // A: 2 tiles per wave
            const int t = w * 2 + t2;
            #pragma unroll
            for (int ph = 0; ph < 2; ph++)
                __builtin_amdgcn_global_load_lds(
                    (const __attribute__((address_space(1))) void*)
                        (AgL + (size_t)(t * 16) * DIM + k0 + ph * 16),
                    (__attribute__((address_space(3))) void*)
                        (As + t * 2048 + ph * 1024),
                    16, 0, 0);
        }
        #pragma unroll
        for (int ph = 0; ph < 2; ph++)          // B: 1 tile per wave
            __builtin_amdgcn_global_load_lds(
                (const __attribute__((address_space(1))) void*)
                    (BgL + (size_t)(w * 16) * DIM + k0 + ph * 16),
                (__attribute__((address_space(3))) void*)
                    (Bs + w * 2048 + ph * 1024),
                16, 0, 0);
        __syncthreads();  // vmcnt drained by barrier semantics

        int8v bf[4];
        #pragma unroll
        for (int j = 0; j < 4; j++) {
            union { int8v v; struct { int4v lo, hi; } s; } u;
            u.s.lo = *(const int4v*)(bRd + j * 2048);
            u.s.hi = *(const int4v*)(bRd + j * 2048 + 1024);
            bf[j] = u.v;
        }

        #pragma unroll
        for (int i = 0; i < 2; i++) {
            union { int8v v; struct { int4v lo, hi; } s; } ua;
            ua.s.lo = *(const int4v*)(aRd + i * 2048);
            ua.s.hi = *(const int4v*)(aRd + i * 2048 + 1024);
            const int8v a = ua.v;
            #pragma unroll
            for (int j = 0; j < 4; j++)
                acc[i][j] = __builtin_amdgcn_mfma_scale_f32_16x16x128_f8f6f4(
                    a, bf[j], acc[i][j],
                    0, 0,               // cbsz=FP8(e4m3), blgp=FP8(e4m3)
                    0, 0x7F7F7F7F,      // opselA, scaleA = 1.0
                    0, 0x7F7F7F7F);     // opselB, scaleB = 1.0
        }
    }

    // Epilogue: per-row max over this block's 64 columns (all in this wave).
    // C/D layout (m89/m91): col = lane&15, row = (lane>>4)*4 + reg.
    const int stripe = blockIdx.x;
    #pragma unroll
    for (int i = 0; i < 2; i++) {
        #pragma unroll
        for (int r = 0; r < 4; r++) {
            float v = fmaxf(fmaxf(acc[i][0][r], acc[i][1][r]),
                            fmaxf(acc[i][2][r], acc[i][3][r]));
            v = fmaxf(v, __shfl_xor(v, 1));
            v = fmaxf(v, __shfl_xor(v, 2));
            v = fmaxf(v, __shfl_xor(v, 4));
            v = fmaxf(v, __shfl_xor(v, 8));
            if (m == 0) {
                const int row = rowBase + w * 32 + i * 16 + q * 4 + r;
                partial[(size_t)row * 128 + stripe] = v;   // = 256 * cos
            }
        }
    }
}

// ---------------- Kernel 3: stripe-max -> loss terms -> per-block partials --
__global__ __launch_bounds__(256) void reduce_kernel(
    const float* __restrict__ partial,
    const float* __restrict__ posdist,
    float* __restrict__ blockpart)   // [64][3]
{
    const int tid  = threadIdx.x;
    const int lane = tid & 63;
    const int w    = tid >> 6;
    __shared__ float red[4][3];

    float sloss = 0.f, spos = 0.f, shard = 0.f;

    #pragma unroll 4
    for (int i = 0; i < 32; i++) {
        const int row = blockIdx.x * 128 + w * 32 + i;
        float v = fmaxf(partial[(size_t)row * 128 + lane],
                        partial[(size_t)row * 128 + 64 + lane]);
        #pragma unroll
        for (int off = 1; off < 64; off <<= 1) v = fmaxf(v, __shfl_xor(v, off));
        if (lane == 0) {
            // v = 256*cos  ->  hard = (2 - 2*cos)/T = (2 - v/128)*TINV
            const float hard = (2.0f - 2.0f * v * INV_QSQ) * TINV;
            const float pos  = posdist[row];
            sloss += fmaxf(MARGIN + pos - hard, 0.0f);
            spos  += pos;
            shard += hard;
        }
    }
    if (lane == 0) { red[w][0] = sloss; red[w][1] = spos; red[w][2] = shard; }
    __syncthreads();
    if (tid == 0) {
        #pragma unroll
        for (int k = 0; k < 3; k++)
            blockpart[blockIdx.x * 3 + k] =
                red[0][k] + red[1][k] + red[2][k] + red[3][k];
    }
}

// ---------------- Kernel 4: finalize means (one wave, no atomics) -----------
__global__ __launch_bounds__(64) void finalize_kernel(
    const float* __restrict__ blockpart,
    float* __restrict__ out)
{
    const int lane = threadIdx.x;
    float a = blockpart[lane * 3 + 0];
    float b = blockpart[lane * 3 + 1];
    float c = blockpart[lane * 3 + 2];
    #pragma unroll
    for (int off = 1; off < 64; off <<= 1) {
        a += __shfl_xor(a, off);
        b += __shfl_xor(b, off);
        c += __shfl_xor(c, off);
    }
    if (lane == 0) {
        const float inv = 1.0f / (float)BS;
        out[0] = a * inv;
        out[1] = b * inv;
        out[2] = c * inv;
    }
}

extern "C" void kernel_launch(void* const* d_in, const int* in_sizes, int n_in,
                              void* d_out, int out_size, void* d_ws, size_t ws_size,
                              hipStream_t stream) {
    const float* feat = (const float*)d_in[0];
    char* ws = (char*)d_ws;

    // ws layout: Afp8 8MiB | Nfp8 8MiB | partial 4MiB | posdist 32KiB | blockpart
    unsigned char* Afp8      = (unsigned char*)ws;
    unsigned char* Nfp8      = (unsigned char*)(ws + ((size_t)8 << 20));
    float*         partial   = (float*)(ws + ((size_t)16 << 20));
    float*         posdist   = (float*)(ws + ((size_t)20 << 20));
    float*         blockpart = (float*)(ws + ((size_t)20 << 20) + 32768);

    normalize_kernel<<<BS / 4, 256, 0, stream>>>(feat, Afp8, Nfp8, posdist);

    maxgemm_kernel<<<dim3(BS / BN, BS / BM), 256, 0, stream>>>(Afp8, Nfp8, partial);

    reduce_kernel<<<64, 256, 0, stream>>>(partial, posdist, blockpart);
    finalize_kernel<<<1, 64, 0, stream>>>(blockpart, (float*)d_out);
}